// Round 6
// baseline (135.073 us; speedup 1.0000x reference)
//
#include <hip/hip_runtime.h>
#include <math.h>

#define GSZ 512
#define NSZ 256
#define NBATCH 8
#define MPTS 131072
#define PI_F 3.14159265358979f
#define BETA_F 13.8551004f
#define BETA2_F (BETA_F * BETA_F)
#define RSQ2 0.70710678f
// LDS pad: +1 float2 every 8 → strided radix-8 access conflict-reduced
#define PADIDX(i) ((i) + ((i) >> 3))

// ---------------------------------------------------------------- helpers

__device__ __forceinline__ float apod(int i) {
    float x = (float)(i - 128);
    float arg = PI_F * 6.0f * x * (1.0f / 512.0f);
    float t = BETA2_F - arg * arg;
    float st = sqrtf(t);
    return st / sinhf(st);
}

// Branchless Kaiser-Bessel weight: w(u) = i0(beta*sqrt(1-(u/3)^2)) inside
// |u|<3 else 0. Uses the large-x asymptotic i0(x) ~ e^x/sqrt(2*pi*x) *
// (1 + 1/(8x) + 9/(128x^2)) for ALL x (clamped to >=0.35). Central taps
// always have x>=13 (err ~3e-5); edge taps (x<4, w<=9 vs center ~1.1e5)
// tolerate the few-% error there — abs weight err <=0.5 is ~4e-6 of the
// center product. No divergence, ~13 VALU.
__device__ __forceinline__ float kbw(float u) {
    float t = 1.0f - u * u * (1.0f / 9.0f);
    float x = BETA_F * sqrtf(fmaxf(t, 0.0f));
    float xc = fmaxf(x, 0.35f);
    float r = __builtin_amdgcn_rcpf(xc);
    float poly = 1.0f + r * (0.125f + r * 0.0703125f);
    float w = __expf(xc) * __builtin_amdgcn_rsqf(6.2831853f * xc) * poly;
    return (t > 0.0f) ? w : 0.0f;
}

__device__ __forceinline__ float2 cadd(float2 a, float2 b){ return make_float2(a.x+b.x, a.y+b.y); }
__device__ __forceinline__ float2 csub(float2 a, float2 b){ return make_float2(a.x-b.x, a.y-b.y); }
__device__ __forceinline__ float2 cmul(float2 a, float2 b){ return make_float2(a.x*b.x-a.y*b.y, a.x*b.y+a.y*b.x); }
__device__ __forceinline__ float2 mul_negi(float2 a){ return make_float2(a.y, -a.x); }
__device__ __forceinline__ float2 mul_posi(float2 a){ return make_float2(-a.y, a.x); }
__device__ __forceinline__ float2 mul_w81(float2 a){ return make_float2(RSQ2*(a.x+a.y), RSQ2*(a.y-a.x)); }
__device__ __forceinline__ float2 mul_w83(float2 a){ return make_float2(RSQ2*(a.y-a.x), -RSQ2*(a.x+a.y)); }

__device__ __forceinline__ void dft8_combine(float2 E0, float2 E1, float2 E2, float2 E3,
                                             float2 O0, float2 O1, float2 O2, float2 O3,
                                             float2* y) {
    float2 c1 = mul_w81(O1), c2 = mul_negi(O2), c3 = mul_w83(O3);
    y[0] = cadd(E0, O0); y[4] = csub(E0, O0);
    y[1] = cadd(E1, c1); y[5] = csub(E1, c1);
    y[2] = cadd(E2, c2); y[6] = csub(E2, c2);
    y[3] = cadd(E3, c3); y[7] = csub(E3, c3);
}

__device__ __forceinline__ void dft8(const float2* x, float2* y) {
    float2 a0=x[0], a1=x[2], a2=x[4], a3=x[6];
    float2 b0=x[1], b1=x[3], b2=x[5], b3=x[7];
    float2 ta0=cadd(a0,a2), ta1=csub(a0,a2), ta2=cadd(a1,a3), ta3=csub(a1,a3);
    float2 E0=cadd(ta0,ta2), E2=csub(ta0,ta2);
    float2 E1=cadd(ta1, mul_negi(ta3)), E3=cadd(ta1, mul_posi(ta3));
    float2 tb0=cadd(b0,b2), tb1=csub(b0,b2), tb2=cadd(b1,b3), tb3=csub(b1,b3);
    float2 O0=cadd(tb0,tb2), O2=csub(tb0,tb2);
    float2 O1=cadd(tb1, mul_negi(tb3)), O3=cadd(tb1, mul_posi(tb3));
    dft8_combine(E0,E1,E2,E3,O0,O1,O2,O3,y);
}

__device__ __forceinline__ void dft8_pruned(float2 x0, float2 x1, float2 x6, float2 x7, float2* y) {
    float2 E0 = cadd(x0, x6), E2 = csub(x0, x6);
    float2 E1 = cadd(x0, mul_posi(x6)), E3 = cadd(x0, mul_negi(x6));
    float2 O0 = cadd(x1, x7), O2 = csub(x1, x7);
    float2 O1 = cadd(x1, mul_posi(x7)), O3 = cadd(x1, mul_negi(x7));
    dft8_combine(E0,E1,E2,E3,O0,O1,O2,O3,y);
}

template<int S>
__device__ __forceinline__ void twiddle8(int t, float2* y) {
    if (S < 2) {
        int j = (S == 0) ? t : (t >> 3);
        const float scale = (S == 0) ? (-2.0f*PI_F/512.0f) : (-2.0f*PI_F/64.0f);
        float theta = scale * (float)j;
        float sn, cs;
        __sincosf(theta, &sn, &cs);              // sin FIRST, cos second
        float2 w = make_float2(cs, sn), wq = w;
        y[1] = cmul(y[1], wq);
        #pragma unroll
        for (int q = 2; q < 8; ++q) { wq = cmul(wq, w); y[q] = cmul(y[q], wq); }
    }
}

// ---------------------------------------------------------------- pass 1
// Wave-synchronous radix-8 row FFT: 64-thread (1-wave) blocks, one row per
// block, single in-place LDS buffer, NO barriers (lockstep: all lanes'
// stage-reads issue before any lane's stage-writes; DS pipe is in-order).
// T compact: 256 nonzero rows, rp<128 <-> y=rp, rp>=128 <-> y=rp+256.
__global__ __launch_bounds__(64) void pass1_rowfft(const float* __restrict__ image,
                                                   float2* __restrict__ T) {
    __shared__ float2 A[578];
    int t = threadIdx.x;
    int blk = blockIdx.x;
    int b = blk & 7;
    int rp = blk >> 3;                              // compact row 0..255
    int y = (rp < 128) ? rp : (rp + 256);
    int iy = (y < 128) ? (y + 128) : (y - 384);
    float ay = apod(iy);
    const float* irow = image + ((size_t)(b * NSZ + iy)) * NSZ;

    float2 y8[8];
    { // stage 0 (pruned, from global): shifted x[p]=s[t+64p], nonzero p=0,1,6,7
        int ix0 = t + 128, ix1 = t + 192, ix6 = t, ix7 = t + 64;
        float2 x0 = make_float2(irow[ix0] * ay * apod(ix0), 0.f);
        float2 x1 = make_float2(irow[ix1] * ay * apod(ix1), 0.f);
        float2 x6 = make_float2(irow[ix6] * ay * apod(ix6), 0.f);
        float2 x7 = make_float2(irow[ix7] * ay * apod(ix7), 0.f);
        dft8_pruned(x0, x1, x6, x7, y8);
        twiddle8<0>(t, y8);
    }
    #pragma unroll
    for (int q = 0; q < 8; ++q) A[PADIDX((t << 3) + q)] = y8[q];
    { // stage 1
        float2 x[8];
        #pragma unroll
        for (int p = 0; p < 8; ++p) x[p] = A[PADIDX(t + (p << 6))];
        dft8(x, y8);
        twiddle8<1>(t, y8);
        int j = t >> 3, k = t & 7, base = k + (j << 6);
        #pragma unroll
        for (int q = 0; q < 8; ++q) A[PADIDX(base + (q << 3))] = y8[q];
    }
    { // stage 2 -> global, natural order
        float2 x[8];
        #pragma unroll
        for (int p = 0; p < 8; ++p) x[p] = A[PADIDX(t + (p << 6))];
        dft8(x, y8);
        float2* Trow = T + (((size_t)(b << 8) + rp) << 9);
        #pragma unroll
        for (int q = 0; q < 8; ++q) Trow[t + (q << 6)] = y8[q];
    }
}

// ---------------------------------------------------------------- pass 2
// Wave-synchronous radix-8 column FFT: 64-thread blocks, 4 columns per
// block (sequential per-col stage loops), single in-place LDS buffer per
// column, no barriers. T compact (256 rows): pruned stage-0 taps at compact
// rows {t, t+64, t+128, t+192}.
__global__ __launch_bounds__(64) void pass2_colfft(const float2* __restrict__ T,
                                                   float2* __restrict__ kgrid) {
    __shared__ float2 B[4][578];
    int t = threadIdx.x;
    int blk = blockIdx.x;
    int b = blk & 7;
    int colbase = (blk >> 3) << 2;                  // 0..508 step 4
    const float2* Tb = T + ((size_t)b << 17);       // 256*512 per batch
    float2* Kb = kgrid + ((size_t)b << 18);

    { // load: 256 compact rows x 4 cols; 4 lanes = 32B contiguous
        int c = t & 3, r0 = t >> 2;                 // r0 0..15
        #pragma unroll
        for (int k = 0; k < 16; ++k) {
            int rr = r0 + (k << 4);
            B[c][PADIDX(rr)] = Tb[((size_t)rr << 9) + colbase + c];
        }
    }
    #pragma unroll
    for (int c = 0; c < 4; ++c) {
        float2* Bc = B[c];
        float2 y8[8];
        { // stage 0 (pruned)
            float2 x0 = Bc[PADIDX(t)];
            float2 x1 = Bc[PADIDX(t + 64)];
            float2 x6 = Bc[PADIDX(t + 128)];
            float2 x7 = Bc[PADIDX(t + 192)];
            dft8_pruned(x0, x1, x6, x7, y8);
            twiddle8<0>(t, y8);
            #pragma unroll
            for (int q = 0; q < 8; ++q) Bc[PADIDX((t << 3) + q)] = y8[q];
        }
        { // stage 1
            float2 x[8];
            #pragma unroll
            for (int p = 0; p < 8; ++p) x[p] = Bc[PADIDX(t + (p << 6))];
            dft8(x, y8);
            twiddle8<1>(t, y8);
            int j = t >> 3, k = t & 7, base = k + (j << 6);
            #pragma unroll
            for (int q = 0; q < 8; ++q) Bc[PADIDX(base + (q << 3))] = y8[q];
        }
        { // stage 2, natural order back to LDS
            float2 x[8];
            #pragma unroll
            for (int p = 0; p < 8; ++p) x[p] = Bc[PADIDX(t + (p << 6))];
            dft8(x, y8);
            #pragma unroll
            for (int q = 0; q < 8; ++q) Bc[PADIDX(t + (q << 6))] = y8[q];
        }
    }
    { // store: 512 rows x 4 cols
        int c = t & 3, r0 = t >> 2;
        #pragma unroll
        for (int k = 0; k < 32; ++k) {
            int rr = r0 + (k << 4);
            Kb[((size_t)rr << 9) + colbase + c] = B[c][PADIDX(rr)];
        }
    }
}

// ---------------------------------------------------------------- pass 3
// Wave-cooperative KB gather: 8 lanes/point, branchless-asymptotic weights,
// grid-strided 512 points/block. b = blk&7 keeps each batch's 2 MB grid
// L2-resident on one XCD.
__global__ __launch_bounds__(256) void interp_kb(const float* __restrict__ ktraj,
                                                 const float* __restrict__ dcf,
                                                 const float2* __restrict__ kgrid,
                                                 float* __restrict__ out) {
    int tid = threadIdx.x;
    int blk = blockIdx.x;
    int b = blk & 7;                          // XCD affinity
    int gb = blk >> 3;                        // 0..255
    int j = tid & 7;                          // lane within 8-lane group
    int gloc = tid >> 3;                      // group in block 0..31
    int lane = tid & 63;
    int gbase = lane & 56;

    const float SCALE = (float)GSZ / (2.0f * PI_F);
    const float2* Kb = kgrid + ((size_t)b << 18);
    const float* kt1 = ktraj + ((size_t)(b * 2)) * MPTS;
    const float* kt2 = kt1 + MPTS;
    const float* dcfb = dcf + ((size_t)b << 17);
    float* out_re = out + ((size_t)b << 17);
    float* out_im = out_re + (size_t)NBATCH * MPTS;

    int m0 = (gb << 9) + gloc;                // block covers [gb*512, gb*512+512)
    #pragma unroll 2
    for (int it = 0; it < 16; ++it) {
        int m = m0 + (it << 5);
        float tm1 = kt1[m] * SCALE;
        float tm2 = kt2[m] * SCALE;
        float f1 = floorf(tm1), f2 = floorf(tm2);
        int if1 = (int)f1, if2 = (int)f2;

        float w2_own = kbw(tm2 - f2 - (float)(j - 2));
        int   i2_own = (if2 + j - 2) & 511;
        float w1_own = kbw(tm1 - f1 - (float)(j - 2));

        float s_re = 0.f, s_im = 0.f;
        #pragma unroll
        for (int a = 0; a < 6; ++a) {
            int i1a = (if1 + a - 2) & 511;
            float w1a = __shfl(w1_own, gbase + a, 64);
            float2 v = Kb[((size_t)i1a << 9) + i2_own];
            s_re = fmaf(w1a, v.x, s_re);
            s_im = fmaf(w1a, v.y, s_im);
        }
        float p_re = w2_own * s_re;
        float p_im = w2_own * s_im;
        #pragma unroll
        for (int d = 1; d < 8; d <<= 1) {
            p_re += __shfl_xor(p_re, d, 64);
            p_im += __shfl_xor(p_im, d, 64);
        }
        float dd = dcfb[m];
        if (j == 0) out_re[m] = p_re * dd;
        if (j == 1) out_im[m] = p_im * dd;
    }
}

// ---------------------------------------------------------------- launch

extern "C" void kernel_launch(void* const* d_in, const int* in_sizes, int n_in,
                              void* d_out, int out_size, void* d_ws, size_t ws_size,
                              hipStream_t stream) {
    const float* image = (const float*)d_in[0];   // (8,256,256) f32
    const float* ktraj = (const float*)d_in[1];   // (8,2,131072) f32
    const float* dcf   = (const float*)d_in[2];   // (8,131072) f32
    float* out = (float*)d_out;                   // (2,8,131072) f32

    float2* T     = (float2*)d_ws;                        // 8*256*512 c64 = 8.4 MB
    float2* kgrid = T + (size_t)NBATCH * 256 * GSZ;       // 8*512*512 c64 = 16.8 MB

    pass1_rowfft<<<NBATCH * 256, 64, 0, stream>>>(image, T);   // 1 row/block
    pass2_colfft<<<NBATCH * 128, 64, 0, stream>>>(T, kgrid);   // 4 cols/block
    interp_kb<<<NBATCH * 256, 256, 0, stream>>>(ktraj, dcf, kgrid, out);
}

// Round 7
// 128.512 us; speedup vs baseline: 1.0511x; 1.0511x over previous
//
#include <hip/hip_runtime.h>
#include <math.h>

#define GSZ 512
#define NSZ 256
#define NBATCH 8
#define MPTS 131072
#define PI_F 3.14159265358979f
#define BETA_F 13.8551004f
#define BETA2_F (BETA_F * BETA_F)
#define RSQ2 0.70710678f
// LDS pad: +1 float2 every 8 → strided radix-8 access conflict-reduced
#define PADIDX(i) ((i) + ((i) >> 3))

// ---------------------------------------------------------------- helpers

__device__ __forceinline__ float apod(int i) {
    float x = (float)(i - 128);
    float arg = PI_F * 6.0f * x * (1.0f / 512.0f);
    float t = BETA2_F - arg * arg;
    float st = sqrtf(t);
    return st / sinhf(st);
}

// Branchless Kaiser-Bessel weight (large-x asymptotic i0, see round-6 notes):
// central taps x>=13 (err ~3e-5); edge taps' few-% error is ~4e-6 of the
// center product. ~13 VALU, no divergence.
__device__ __forceinline__ float kbw(float u) {
    float t = 1.0f - u * u * (1.0f / 9.0f);
    float x = BETA_F * sqrtf(fmaxf(t, 0.0f));
    float xc = fmaxf(x, 0.35f);
    float r = __builtin_amdgcn_rcpf(xc);
    float poly = 1.0f + r * (0.125f + r * 0.0703125f);
    float w = __expf(xc) * __builtin_amdgcn_rsqf(6.2831853f * xc) * poly;
    return (t > 0.0f) ? w : 0.0f;
}

// DPP quad_perm (VALU-integrated cross-lane within each aligned 4-lane quad)
template<int CTRL>
__device__ __forceinline__ float qdpp(float v) {
    int r = __builtin_amdgcn_mov_dpp(__float_as_int(v), CTRL, 0xF, 0xF, true);
    return __int_as_float(r);
}
// broadcast lane L within quad: CTRL = L*0x55
// xor1 swap: [1,0,3,2] = 0xB1 ; xor2 swap: [2,3,0,1] = 0x4E

struct __align__(8) F4 { float x, y, z, w; };   // 2 float2 taps, 8B-aligned

__device__ __forceinline__ float2 cadd(float2 a, float2 b){ return make_float2(a.x+b.x, a.y+b.y); }
__device__ __forceinline__ float2 csub(float2 a, float2 b){ return make_float2(a.x-b.x, a.y-b.y); }
__device__ __forceinline__ float2 cmul(float2 a, float2 b){ return make_float2(a.x*b.x-a.y*b.y, a.x*b.y+a.y*b.x); }
__device__ __forceinline__ float2 mul_negi(float2 a){ return make_float2(a.y, -a.x); }
__device__ __forceinline__ float2 mul_posi(float2 a){ return make_float2(-a.y, a.x); }
__device__ __forceinline__ float2 mul_w81(float2 a){ return make_float2(RSQ2*(a.x+a.y), RSQ2*(a.y-a.x)); }
__device__ __forceinline__ float2 mul_w83(float2 a){ return make_float2(RSQ2*(a.y-a.x), -RSQ2*(a.x+a.y)); }

__device__ __forceinline__ void dft8_combine(float2 E0, float2 E1, float2 E2, float2 E3,
                                             float2 O0, float2 O1, float2 O2, float2 O3,
                                             float2* y) {
    float2 c1 = mul_w81(O1), c2 = mul_negi(O2), c3 = mul_w83(O3);
    y[0] = cadd(E0, O0); y[4] = csub(E0, O0);
    y[1] = cadd(E1, c1); y[5] = csub(E1, c1);
    y[2] = cadd(E2, c2); y[6] = csub(E2, c2);
    y[3] = cadd(E3, c3); y[7] = csub(E3, c3);
}

__device__ __forceinline__ void dft8(const float2* x, float2* y) {
    float2 a0=x[0], a1=x[2], a2=x[4], a3=x[6];
    float2 b0=x[1], b1=x[3], b2=x[5], b3=x[7];
    float2 ta0=cadd(a0,a2), ta1=csub(a0,a2), ta2=cadd(a1,a3), ta3=csub(a1,a3);
    float2 E0=cadd(ta0,ta2), E2=csub(ta0,ta2);
    float2 E1=cadd(ta1, mul_negi(ta3)), E3=cadd(ta1, mul_posi(ta3));
    float2 tb0=cadd(b0,b2), tb1=csub(b0,b2), tb2=cadd(b1,b3), tb3=csub(b1,b3);
    float2 O0=cadd(tb0,tb2), O2=csub(tb0,tb2);
    float2 O1=cadd(tb1, mul_negi(tb3)), O3=cadd(tb1, mul_posi(tb3));
    dft8_combine(E0,E1,E2,E3,O0,O1,O2,O3,y);
}

__device__ __forceinline__ void dft8_pruned(float2 x0, float2 x1, float2 x6, float2 x7, float2* y) {
    float2 E0 = cadd(x0, x6), E2 = csub(x0, x6);
    float2 E1 = cadd(x0, mul_posi(x6)), E3 = cadd(x0, mul_negi(x6));
    float2 O0 = cadd(x1, x7), O2 = csub(x1, x7);
    float2 O1 = cadd(x1, mul_posi(x7)), O3 = cadd(x1, mul_negi(x7));
    dft8_combine(E0,E1,E2,E3,O0,O1,O2,O3,y);
}

template<int S>
__device__ __forceinline__ void twiddle8(int t, float2* y) {
    if (S < 2) {
        int j = (S == 0) ? t : (t >> 3);
        const float scale = (S == 0) ? (-2.0f*PI_F/512.0f) : (-2.0f*PI_F/64.0f);
        float theta = scale * (float)j;
        float sn, cs;
        __sincosf(theta, &sn, &cs);              // sin FIRST, cos second
        float2 w = make_float2(cs, sn), wq = w;
        y[1] = cmul(y[1], wq);
        #pragma unroll
        for (int q = 2; q < 8; ++q) { wq = cmul(wq, w); y[q] = cmul(y[q], wq); }
    }
}

// ---------------------------------------------------------------- pass 1
// (round-5 version: 4 rows/block, barriers, compact 256-row T)
__global__ __launch_bounds__(256) void pass1_rowfft(const float* __restrict__ image,
                                                    float2* __restrict__ T) {
    __shared__ float2 sm[2][4][578];
    int tid = threadIdx.x;
    int r = tid >> 6, t = tid & 63;
    int blk = blockIdx.x;
    int b = blk & 7;
    int g = blk >> 3;                               // 0..63
    int rp = (g << 2) + r;                          // compact row 0..255
    int y = (rp < 128) ? rp : (rp + 256);
    int iy = (y < 128) ? (y + 128) : (y - 384);
    float ay = apod(iy);
    const float* irow = image + ((size_t)(b * NSZ + iy)) * NSZ;

    float2 y8[8];
    {
        int ix0 = t + 128, ix1 = t + 192, ix6 = t, ix7 = t + 64;
        float2 x0 = make_float2(irow[ix0] * ay * apod(ix0), 0.f);
        float2 x1 = make_float2(irow[ix1] * ay * apod(ix1), 0.f);
        float2 x6 = make_float2(irow[ix6] * ay * apod(ix6), 0.f);
        float2 x7 = make_float2(irow[ix7] * ay * apod(ix7), 0.f);
        dft8_pruned(x0, x1, x6, x7, y8);
        twiddle8<0>(t, y8);
    }
    float2* A  = sm[0][r];
    float2* Bf = sm[1][r];
    #pragma unroll
    for (int q = 0; q < 8; ++q) A[PADIDX((t << 3) + q)] = y8[q];
    __syncthreads();
    {
        float2 x[8];
        #pragma unroll
        for (int p = 0; p < 8; ++p) x[p] = A[PADIDX(t + (p << 6))];
        dft8(x, y8);
        twiddle8<1>(t, y8);
        int j = t >> 3, k = t & 7, base = k + (j << 6);
        #pragma unroll
        for (int q = 0; q < 8; ++q) Bf[PADIDX(base + (q << 3))] = y8[q];
    }
    __syncthreads();
    {
        float2 x[8];
        #pragma unroll
        for (int p = 0; p < 8; ++p) x[p] = Bf[PADIDX(t + (p << 6))];
        dft8(x, y8);
        float2* Trow = T + (((size_t)(b << 8) + rp) << 9);
        #pragma unroll
        for (int q = 0; q < 8; ++q) Trow[t + (q << 6)] = y8[q];
    }
}

// ---------------------------------------------------------------- pass 2
// (round-5 version: 8 cols/block, single LDS buffer, full 64B lines)
__global__ __launch_bounds__(256) void pass2_colfft(const float2* __restrict__ T,
                                                    float2* __restrict__ kgrid) {
    __shared__ float2 B[8][578];
    int tid = threadIdx.x;
    int blk = blockIdx.x;
    int b = blk & 7;
    int colbase = (blk >> 3) << 3;                  // 0..504 step 8
    const float2* Tb = T + ((size_t)b << 17);       // 256*512 per batch
    float2* Kb = kgrid + ((size_t)b << 18);

    {
        int c = tid & 7, r0 = tid >> 3;             // r0 0..31
        #pragma unroll
        for (int k = 0; k < 8; ++k) {
            int rr = r0 + (k << 5);
            B[c][PADIDX(rr)] = Tb[((size_t)rr << 9) + colbase + c];
        }
    }
    __syncthreads();
    int t = tid & 63;
    int c0 = tid >> 6;                              // cols c0 and c0+4
    float2 ya[8], yb[8];
    {
        float2* Ba = B[c0];
        float2* Bb = B[c0 + 4];
        float2 a0 = Ba[PADIDX(t)],   a1 = Ba[PADIDX(t + 64)];
        float2 a6 = Ba[PADIDX(t + 128)], a7 = Ba[PADIDX(t + 192)];
        float2 b0 = Bb[PADIDX(t)],   b1 = Bb[PADIDX(t + 64)];
        float2 b6 = Bb[PADIDX(t + 128)], b7 = Bb[PADIDX(t + 192)];
        dft8_pruned(a0, a1, a6, a7, ya); twiddle8<0>(t, ya);
        dft8_pruned(b0, b1, b6, b7, yb); twiddle8<0>(t, yb);
    }
    __syncthreads();
    #pragma unroll
    for (int q = 0; q < 8; ++q) {
        B[c0][PADIDX((t << 3) + q)]     = ya[q];
        B[c0 + 4][PADIDX((t << 3) + q)] = yb[q];
    }
    __syncthreads();
    {
        float2 xa[8], xb[8];
        #pragma unroll
        for (int p = 0; p < 8; ++p) { xa[p] = B[c0][PADIDX(t + (p << 6))]; xb[p] = B[c0 + 4][PADIDX(t + (p << 6))]; }
        dft8(xa, ya); twiddle8<1>(t, ya);
        dft8(xb, yb); twiddle8<1>(t, yb);
    }
    __syncthreads();
    {
        int j = t >> 3, k = t & 7, base = k + (j << 6);
        #pragma unroll
        for (int q = 0; q < 8; ++q) {
            B[c0][PADIDX(base + (q << 3))]     = ya[q];
            B[c0 + 4][PADIDX(base + (q << 3))] = yb[q];
        }
    }
    __syncthreads();
    {
        float2 xa[8], xb[8];
        #pragma unroll
        for (int p = 0; p < 8; ++p) { xa[p] = B[c0][PADIDX(t + (p << 6))]; xb[p] = B[c0 + 4][PADIDX(t + (p << 6))]; }
        dft8(xa, ya);
        dft8(xb, yb);
    }
    __syncthreads();
    #pragma unroll
    for (int q = 0; q < 8; ++q) {
        B[c0][PADIDX(t + (q << 6))]     = ya[q];
        B[c0 + 4][PADIDX(t + (q << 6))] = yb[q];
    }
    __syncthreads();
    {
        int c = tid & 7, r0 = tid >> 3;
        #pragma unroll
        for (int k = 0; k < 16; ++k) {
            int rr = r0 + (k << 5);
            Kb[((size_t)rr << 9) + colbase + c] = B[c][PADIDX(rr)];
        }
    }
}

// ---------------------------------------------------------------- pass 3
// Quad-cooperative KB gather: 4 lanes per point, DPP-only cross-lane (zero
// DS-pipe traffic). Lane j owns col pair (e0+2j, e0+2j+1) where e0 is the
// even-aligned base col (covers the 6-tap window; extra cols weight 0, and
// an even pair never straddles the 512 wrap). Per row: one 16B load of 2
// taps. w1[a] comes from quad_perm broadcasts (lane j computes rows j and
// j+4); final sum via 2 quad_perm-xor DPPs. 16 points/wave.
__global__ __launch_bounds__(256) void interp_kb(const float* __restrict__ ktraj,
                                                 const float* __restrict__ dcf,
                                                 const float2* __restrict__ kgrid,
                                                 float* __restrict__ out) {
    int tid = threadIdx.x;
    int blk = blockIdx.x;
    int b = blk & 7;                          // XCD affinity
    int gb = blk >> 3;                        // 0..255
    int j = tid & 3;                          // lane within quad
    int q = tid >> 2;                         // quad in block 0..63

    const float SCALE = (float)GSZ / (2.0f * PI_F);
    const float2* Kb = kgrid + ((size_t)b << 18);
    const float* kt1 = ktraj + ((size_t)(b * 2)) * MPTS;
    const float* kt2 = kt1 + MPTS;
    const float* dcfb = dcf + ((size_t)b << 17);
    float* out_re = out + ((size_t)b << 17);
    float* out_im = out_re + (size_t)NBATCH * MPTS;

    int m0 = (gb << 9) + q;                   // block covers 512 points
    #pragma unroll 2
    for (int it = 0; it < 8; ++it) {
        int m = m0 + (it << 6);
        float tm1 = kt1[m] * SCALE;
        float tm2 = kt2[m] * SCALE;
        float f1 = floorf(tm1), f2 = floorf(tm2);
        int if1 = (int)f1, if2 = (int)f2;
        int e0 = (if2 - 2) & ~1;              // even base col (unwrapped)

        // own col-pair weights (support test zeroes out-of-window cols)
        float u2 = tm2 - (float)(e0 + 2 * j);
        float w2a = kbw(u2);
        float w2b = kbw(u2 - 1.0f);
        int cpair = (e0 + 2 * j) & 511;       // even → pair never wraps mid

        // this lane supplies w1 for rows j and j+4 (rows 6,7 → weight 0)
        float fr1 = tm1 - f1;
        float w1A = kbw(fr1 - (float)(j - 2));
        float w1B = kbw(fr1 - (float)(j + 2));

        float c0re = 0.f, c0im = 0.f, c1re = 0.f, c1im = 0.f;
        #define KB_ROW(a, W, CTRL)                                            \
        {                                                                     \
            float w1a = qdpp<CTRL>(W);                                        \
            int rowb = (if1 + (a) - 2) & 511;                                 \
            F4 v = *reinterpret_cast<const F4*>(Kb + ((size_t)rowb << 9) + cpair); \
            c0re = fmaf(w1a, v.x, c0re); c0im = fmaf(w1a, v.y, c0im);         \
            c1re = fmaf(w1a, v.z, c1re); c1im = fmaf(w1a, v.w, c1im);         \
        }
        KB_ROW(0, w1A, 0x00)
        KB_ROW(1, w1A, 0x55)
        KB_ROW(2, w1A, 0xAA)
        KB_ROW(3, w1A, 0xFF)
        KB_ROW(4, w1B, 0x00)
        KB_ROW(5, w1B, 0x55)
        #undef KB_ROW

        float p_re = fmaf(w2a, c0re, w2b * c1re);
        float p_im = fmaf(w2a, c0im, w2b * c1im);
        // quad reduction via DPP xor-swaps; all 4 lanes end with the sum
        p_re += qdpp<0xB1>(p_re);  p_re += qdpp<0x4E>(p_re);
        p_im += qdpp<0xB1>(p_im);  p_im += qdpp<0x4E>(p_im);

        float dd = dcfb[m];
        if (j == 0) out_re[m] = p_re * dd;
        if (j == 1) out_im[m] = p_im * dd;
    }
}

// ---------------------------------------------------------------- launch

extern "C" void kernel_launch(void* const* d_in, const int* in_sizes, int n_in,
                              void* d_out, int out_size, void* d_ws, size_t ws_size,
                              hipStream_t stream) {
    const float* image = (const float*)d_in[0];   // (8,256,256) f32
    const float* ktraj = (const float*)d_in[1];   // (8,2,131072) f32
    const float* dcf   = (const float*)d_in[2];   // (8,131072) f32
    float* out = (float*)d_out;                   // (2,8,131072) f32

    float2* T     = (float2*)d_ws;                        // 8*256*512 c64 = 8.4 MB
    float2* kgrid = T + (size_t)NBATCH * 256 * GSZ;       // 8*512*512 c64 = 16.8 MB

    pass1_rowfft<<<NBATCH * 64, 256, 0, stream>>>(image, T);    // 256 rows / 4 per block
    pass2_colfft<<<NBATCH * 64, 256, 0, stream>>>(T, kgrid);    // 512 cols / 8 per block
    interp_kb<<<NBATCH * 256, 256, 0, stream>>>(ktraj, dcf, kgrid, out);
}